// Round 5
// baseline (126.170 us; speedup 1.0000x reference)
//
#include <hip/hip_runtime.h>
#include <math.h>

typedef _Float16 half8 __attribute__((ext_vector_type(8)));
typedef _Float16 half4v __attribute__((ext_vector_type(4)));
typedef float floatx4 __attribute__((ext_vector_type(4)));

// ---------------------------------------------------------------------------
// Prep: hi = E@W1a + b1 (fp32), hj = E@W1b (f16); W2/W3 pre-swizzled into
// MFMA fragment order so main kernel register-loads them coalesced.
// blocks 0..1023: one (b,s) row each. block 1024: W2frag. block 1025: W3frag.
// ---------------------------------------------------------------------------
__global__ __launch_bounds__(128) void prep_kernel(
    const float* __restrict__ E,
    const float* __restrict__ W1,
    const float* __restrict__ b1,
    const float* __restrict__ W2,
    const float* __restrict__ W3,
    float* __restrict__ hi,
    _Float16* __restrict__ hjh,
    _Float16* __restrict__ W2frag,
    _Float16* __restrict__ W3frag)
{
    const int blk = blockIdx.x;
    const int t = threadIdx.x;
    if (blk < 1024) {
        __shared__ float sE[128];
        sE[t] = E[blk*128 + t];
        __syncthreads();
        float ai = b1[t];
        float aj = 0.f;
        #pragma unroll 8
        for (int d = 0; d < 128; ++d) {
            float e = sE[d];
            ai = fmaf(e, W1[d*128 + t], ai);
            aj = fmaf(e, W1[(128+d)*128 + t], aj);
        }
        hi[blk*128 + t] = ai;
        hjh[blk*128 + t] = (_Float16)aj;
    } else if (blk == 1024) {
        // A-fragment order: frag g=((wr*4+nt)*4+ks), lane l, elem q holds
        // W2t[n][k] = W2[k][n], n = 64*wr+16*nt+(l&15), k = ks*32+(l>>4)*8+q
        for (int e = t; e < 16384; e += 128) {
            int q = e & 7, l = (e >> 3) & 63, g = e >> 9;
            int wr = g >> 4, nt = (g >> 2) & 3, ks = g & 3;
            int row = 64*wr + 16*nt + (l & 15);
            int k = ks*32 + (l >> 4)*8 + q;
            W2frag[e] = (_Float16)W2[k*128 + row];
        }
    } else {
        // B-fragment order: frag ks, lane l, elem q holds W3[k][n2],
        // n2 = l&15, k = ks*32+(l>>4)*8+q
        for (int e = t; e < 2048; e += 128) {
            int q = e & 7, l = (e >> 3) & 63, ks = e >> 9;
            int k = ks*32 + (l >> 4)*8 + q;
            W3frag[e] = (_Float16)W3[k*16 + (l & 15)];
        }
    }
}

// ---------------------------------------------------------------------------
// Main: one block = (b, i, j0..j0+127). H(128x128) in LDS f16,
// GEMM1 transposed (D[n][m]) for packed H2 write-back, GEMM2 (D[m][n2])
// for float4 per-head-plane global stores. OUTPUT IS FLOAT32.
// ---------------------------------------------------------------------------
__global__ __launch_bounds__(256, 2) void main_kernel(
    const float* __restrict__ hi,
    const _Float16* __restrict__ hjh,
    const _Float16* __restrict__ W2frag,
    const _Float16* __restrict__ W3frag,
    const float* __restrict__ b2,
    const float* __restrict__ b3,
    const float* __restrict__ temps,
    const int* __restrict__ mask,
    float* __restrict__ out)
{
    constexpr int PADH = 136;   // 272B row stride: 4-bank rotation, 16B-aligned
    __shared__ _Float16 sH[128 * PADH];   // H, then reused for H2
    __shared__ float sHi[128];
    __shared__ float sB2[128];

    const int tid = threadIdx.x;
    const int bid = blockIdx.x;
    const int b  = bid >> 11;
    const int i  = (bid >> 2) & 511;
    const int j0 = (bid & 3) << 7;

    const int lane = tid & 63;
    const int wave = tid >> 6;
    const int wr = wave >> 1;   // n-strip of GEMM1'
    const int wc = wave & 1;    // m-strip (j)
    const int lr = lane & 15;
    const int lq = lane >> 4;

    // W2 A-fragments straight to registers (coalesced 1KB/frag, L2-hot)
    half8 aW[4][4];
    const half8* w2v = (const half8*)W2frag;
    #pragma unroll
    for (int nt = 0; nt < 4; ++nt)
        #pragma unroll
        for (int ks = 0; ks < 4; ++ks)
            aW[nt][ks] = w2v[((wr*4 + nt)*4 + ks)*64 + lane];

    if (tid < 128) {
        sHi[tid] = hi[(b*512 + i)*128 + tid];
        sB2[tid] = b2[tid];
    }
    __syncthreads();

    // Build H[j][k] = relu(hi[i][k] + hj[j][k]) as f16
    {
        const int row = tid >> 1;
        const _Float16* hjrow = &hjh[(b*512 + j0 + row)*128];
        #pragma unroll
        for (int kk = 0; kk < 8; ++kk) {
            const int kb = (tid & 1)*8 + kk*16;
            half8 hv = *(const half8*)&hjrow[kb];
            float4 c0 = *(const float4*)&sHi[kb];
            float4 c1 = *(const float4*)&sHi[kb + 4];
            half8 o;
            o[0] = (_Float16)fmaxf((float)hv[0] + c0.x, 0.f);
            o[1] = (_Float16)fmaxf((float)hv[1] + c0.y, 0.f);
            o[2] = (_Float16)fmaxf((float)hv[2] + c0.z, 0.f);
            o[3] = (_Float16)fmaxf((float)hv[3] + c0.w, 0.f);
            o[4] = (_Float16)fmaxf((float)hv[4] + c1.x, 0.f);
            o[5] = (_Float16)fmaxf((float)hv[5] + c1.y, 0.f);
            o[6] = (_Float16)fmaxf((float)hv[6] + c1.z, 0.f);
            o[7] = (_Float16)fmaxf((float)hv[7] + c1.w, 0.f);
            *(half8*)&sH[row*PADH + kb] = o;
        }
    }
    __syncthreads();

    // GEMM1': D[n][m] = sum_k W2[k][n] * H[m][k]  (transposed on purpose)
    floatx4 acc[4][4] = {};
    #pragma unroll
    for (int ks = 0; ks < 4; ++ks) {
        const int k0 = ks*32;
        half8 bF[4];
        #pragma unroll
        for (int mt = 0; mt < 4; ++mt)
            bF[mt] = *(const half8*)&sH[(64*wc + 16*mt + lr)*PADH + k0 + lq*8];
        #pragma unroll
        for (int nt = 0; nt < 4; ++nt)
            #pragma unroll
            for (int mt = 0; mt < 4; ++mt)
                acc[nt][mt] = __builtin_amdgcn_mfma_f32_16x16x32_f16(
                    aW[nt][ks], bF[mt], acc[nt][mt], 0, 0, 0);
    }
    __syncthreads();   // all waves done reading H before overwrite

    // H2[m][n] = relu(D + b2[n]); lane's 4 regs are 4 consecutive n → b64 write
    #pragma unroll
    for (int nt = 0; nt < 4; ++nt) {
        const int nb = 64*wr + 16*nt + 4*lq;
        float4 bv = *(const float4*)&sB2[nb];
        #pragma unroll
        for (int mt = 0; mt < 4; ++mt) {
            const int m = 64*wc + 16*mt + lr;
            floatx4 v = acc[nt][mt];
            half4v o;
            o[0] = (_Float16)fmaxf(v[0] + bv.x, 0.f);
            o[1] = (_Float16)fmaxf(v[1] + bv.y, 0.f);
            o[2] = (_Float16)fmaxf(v[2] + bv.z, 0.f);
            o[3] = (_Float16)fmaxf(v[3] + bv.w, 0.f);
            *(half4v*)&sH[m*PADH + nb] = o;
        }
    }
    __syncthreads();

    // GEMM2: D2[m][n2] = sum_n H2[m][n] * W3[n][n2]
    half8 bW[4];
    const half8* w3v = (const half8*)W3frag;
    #pragma unroll
    for (int ks = 0; ks < 4; ++ks) bW[ks] = w3v[ks*64 + lane];

    floatx4 acc2[2] = {};
    const int m0 = 32*wave;
    #pragma unroll
    for (int ks = 0; ks < 4; ++ks) {
        const int k0 = ks*32;
        half8 a0 = *(const half8*)&sH[(m0 + lr)*PADH + k0 + lq*8];
        half8 a1 = *(const half8*)&sH[(m0 + 16 + lr)*PADH + k0 + lq*8];
        acc2[0] = __builtin_amdgcn_mfma_f32_16x16x32_f16(a0, bW[ks], acc2[0], 0, 0, 0);
        acc2[1] = __builtin_amdgcn_mfma_f32_16x16x32_f16(a1, bW[ks], acc2[1], 0, 0, 0);
    }

    // Epilogue: bias = (comp + b3)*temp, mask→-inf, float4 store (f32 output!)
    const int n2 = lr;
    const float tempv = temps[n2];
    const float b3v = b3[n2];
    const int* mrow = &mask[(b*512 + i)*512];
    float* outp = &out[(((b*16 + n2)*512) + i)*512];
    #pragma unroll
    for (int mt2 = 0; mt2 < 2; ++mt2) {
        const int j = j0 + m0 + 16*mt2 + 4*lq;
        floatx4 v = acc2[mt2];
        int4 mk = *(const int4*)&mrow[j];
        float4 res;
        res.x = mk.x ? (v[0] + b3v)*tempv : -INFINITY;
        res.y = mk.y ? (v[1] + b3v)*tempv : -INFINITY;
        res.z = mk.z ? (v[2] + b3v)*tempv : -INFINITY;
        res.w = mk.w ? (v[3] + b3v)*tempv : -INFINITY;
        *(float4*)&outp[j] = res;
    }
}

extern "C" void kernel_launch(void* const* d_in, const int* in_sizes, int n_in,
                              void* d_out, int out_size, void* d_ws, size_t ws_size,
                              hipStream_t stream)
{
    const float* E     = (const float*)d_in[0];
    const int* mask    = (const int*)d_in[1];
    const float* W1    = (const float*)d_in[2];
    const float* b1    = (const float*)d_in[3];
    const float* W2    = (const float*)d_in[4];
    const float* b2    = (const float*)d_in[5];
    const float* W3    = (const float*)d_in[6];
    const float* b3    = (const float*)d_in[7];
    const float* temps = (const float*)d_in[8];

    char* ws = (char*)d_ws;
    float*    hi  = (float*)ws;                          // 1024*128 f32 = 512KB
    _Float16* hjh = (_Float16*)(ws + 524288);            // 1024*128 f16 = 256KB
    _Float16* W2f = (_Float16*)(ws + 524288 + 262144);   // 16384 f16 = 32KB
    _Float16* W3f = W2f + 16384;                         // 2048 f16 = 4KB

    prep_kernel<<<1026, 128, 0, stream>>>(E, W1, b1, W2, W3, hi, hjh, W2f, W3f);
    main_kernel<<<4096, 256, 0, stream>>>(hi, hjh, W2f, W3f, b2, b3, temps, mask,
                                          (float*)d_out);
}